// Round 15
// baseline (293.255 us; speedup 1.0000x reference)
//
#include <hip/hip_runtime.h>

#define N_NODES 50000
#define DIM     128
#define E_EDGES 800000
#define ELLW    64        // ELL row stride; Poisson(16) in-degree, P(deg > 60) ~ 1e-18

typedef __attribute__((ext_vector_type(8))) short short8;
typedef __attribute__((ext_vector_type(4))) float f32x4;

__device__ __forceinline__ float bflo(unsigned int u){ return __uint_as_float(u << 16); }
__device__ __forceinline__ float bfhi(unsigned int u){ return __uint_as_float(u & 0xFFFF0000u); }
__device__ __forceinline__ unsigned int f2bf(float f){
  unsigned int u = __float_as_uint(f);
  return (u + 0x7FFFu + ((u >> 16) & 1u)) >> 16;
}
__device__ __forceinline__ unsigned int pack2(float a, float b){
  return f2bf(a) | (f2bf(b) << 16);
}

// ---------------- count: atomics + per-edge slot record ----------------

__global__ __launch_bounds__(256) void count_kernel(const int* __restrict__ edges,
                                                    int* __restrict__ cnt,
                                                    int* __restrict__ epos){
  int e = blockIdx.x * 256 + threadIdx.x;
  if (e < E_EDGES) epos[e] = atomicAdd(&cnt[edges[E_EDGES + e]], 1);
}

// ---------------- prep: fill ELL | pad ELL | cvt W -> bf16 Wt^T (block ranges) ------
// ELL entry = 4 B: lo16 = src node id (N<65536), hi16 = bf16 edge weight.
// blocks [0,3125): fill; [3125,3321): pad; [3321,3513): cvtw.

__global__ __launch_bounds__(256) void prep_kernel(const int* __restrict__ edges,
                                                   const int* __restrict__ epos,
                                                   const int* __restrict__ cnt,
                                                   unsigned int* __restrict__ ell,
                                                   const float* __restrict__ W0,
                                                   const float* __restrict__ W1,
                                                   const float* __restrict__ W2,
                                                   unsigned short* __restrict__ Wt){
  int u = blockIdx.x, tid = threadIdx.x;
  if (u < 3125){
    int e = u * 256 + tid;
    if (e < E_EDGES){
      int s = edges[e];
      int d = edges[E_EDGES + e];
      int pos = epos[e];
      if (pos < ELLW){
        float w = rsqrtf((float)(cnt[s] + 1)) * rsqrtf((float)(cnt[d] + 1));
        ell[(size_t)d * ELLW + pos] = (unsigned)s | (f2bf(w) << 16);
      }
    }
  } else if (u < 3125 + 196){
    int i = (u - 3125) * 256 + tid;
    if (i < N_NODES){
      int deg = cnt[i];
      int g4 = i & ~3;   // agg wave covers nodes [g4, g4+4) with shared J
      int J = max(max(cnt[g4], cnt[g4 + 1]), max(cnt[g4 + 2], cnt[g4 + 3]));
      int J4 = min(ELLW, (J + 3) & ~3);
      for (int pp = min(deg, J4); pp < J4; ++pp)
        ell[(size_t)i * ELLW + pp] = 0u;        // src=0, w=+0.0bf16
    }
  } else {
    int idx = (u - 3321) * 256 + tid;   // < 49152
    int w = idx >> 14, r = idx & 16383;
    const float* W = (w == 0) ? W0 : (w == 1) ? W1 : W2;
    Wt[w * 16384 + (r & 127) * 128 + (r >> 7)] = (unsigned short)f2bf(W[r]);
  }
}

// ---------------- GEMM with fused LN+ReLU on fp32 input (layer 0) ----------------

__global__ __launch_bounds__(256) void gemm_ln_mfma(const float* __restrict__ X,
                                                    const float* __restrict__ g,
                                                    const float* __restrict__ bt,
                                                    const unsigned short* __restrict__ Wt,
                                                    unsigned short* __restrict__ Y){
  __shared__ unsigned short ldsb[128 * 136];
  int tid = threadIdx.x;
  #pragma unroll
  for (int it = 0; it < 8; ++it){
    int c  = tid + it * 256;
    int n  = c >> 4, kc = c & 15;
    *(short8*)&ldsb[n * 136 + kc * 8] = *(const short8*)(Wt + n * 128 + kc * 8);
  }
  int wave = tid >> 6, lane = tid & 63, quad = lane >> 4, l15 = lane & 15;
  int rowbase = blockIdx.x * 128 + wave * 32;
  int rm0 = rowbase + l15;      if (rm0 > N_NODES - 1) rm0 = N_NODES - 1;
  int rm1 = rowbase + 16 + l15; if (rm1 > N_NODES - 1) rm1 = N_NODES - 1;

  float v0[4][8], v1[4][8];
  float s0 = 0.f, ss0 = 0.f, s1 = 0.f, ss1 = 0.f;
  #pragma unroll
  for (int kk = 0; kk < 4; ++kk){
    float4 xa = *(const float4*)(X + (size_t)rm0 * 128 + kk * 32 + quad * 8);
    float4 xb = *(const float4*)(X + (size_t)rm0 * 128 + kk * 32 + quad * 8 + 4);
    float4 ya = *(const float4*)(X + (size_t)rm1 * 128 + kk * 32 + quad * 8);
    float4 yb_ = *(const float4*)(X + (size_t)rm1 * 128 + kk * 32 + quad * 8 + 4);
    v0[kk][0]=xa.x; v0[kk][1]=xa.y; v0[kk][2]=xa.z; v0[kk][3]=xa.w;
    v0[kk][4]=xb.x; v0[kk][5]=xb.y; v0[kk][6]=xb.z; v0[kk][7]=xb.w;
    v1[kk][0]=ya.x; v1[kk][1]=ya.y; v1[kk][2]=ya.z; v1[kk][3]=ya.w;
    v1[kk][4]=yb_.x; v1[kk][5]=yb_.y; v1[kk][6]=yb_.z; v1[kk][7]=yb_.w;
    #pragma unroll
    for (int j = 0; j < 8; ++j){
      s0 += v0[kk][j]; ss0 += v0[kk][j] * v0[kk][j];
      s1 += v1[kk][j]; ss1 += v1[kk][j] * v1[kk][j];
    }
  }
  s0 += __shfl_xor(s0, 16, 64); ss0 += __shfl_xor(ss0, 16, 64);
  s0 += __shfl_xor(s0, 32, 64); ss0 += __shfl_xor(ss0, 32, 64);
  s1 += __shfl_xor(s1, 16, 64); ss1 += __shfl_xor(ss1, 16, 64);
  s1 += __shfl_xor(s1, 32, 64); ss1 += __shfl_xor(ss1, 32, 64);
  float mu0 = s0 * (1.0f/128.0f), var0 = ss0 * (1.0f/128.0f) - mu0*mu0;
  float mu1 = s1 * (1.0f/128.0f), var1 = ss1 * (1.0f/128.0f) - mu1*mu1;
  float rs0 = rsqrtf(var0 + 1e-5f), rs1 = rsqrtf(var1 + 1e-5f);

  short8 a0[4], a1[4];
  #pragma unroll
  for (int kk = 0; kk < 4; ++kk){
    float4 ga = *(const float4*)(g  + kk * 32 + quad * 8);
    float4 gb = *(const float4*)(g  + kk * 32 + quad * 8 + 4);
    float4 ba = *(const float4*)(bt + kk * 32 + quad * 8);
    float4 bb = *(const float4*)(bt + kk * 32 + quad * 8 + 4);
    float gg[8] = {ga.x,ga.y,ga.z,ga.w,gb.x,gb.y,gb.z,gb.w};
    float bbv[8] = {ba.x,ba.y,ba.z,ba.w,bb.x,bb.y,bb.z,bb.w};
    #pragma unroll
    for (int j = 0; j < 8; ++j){
      float h0 = fmaxf((v0[kk][j] - mu0) * rs0 * gg[j] + bbv[j], 0.0f);
      float h1 = fmaxf((v1[kk][j] - mu1) * rs1 * gg[j] + bbv[j], 0.0f);
      a0[kk][j] = (short)f2bf(h0);
      a1[kk][j] = (short)f2bf(h1);
    }
  }

  f32x4 acc[2][8];
  #pragma unroll
  for (int mt = 0; mt < 2; ++mt)
    #pragma unroll
    for (int nt = 0; nt < 8; ++nt) acc[mt][nt] = (f32x4){0.f, 0.f, 0.f, 0.f};
  __syncthreads();
  #pragma unroll
  for (int kk = 0; kk < 4; ++kk){
    #pragma unroll
    for (int nt = 0; nt < 8; ++nt){
      short8 b = *(const short8*)&ldsb[(nt * 16 + l15) * 136 + kk * 32 + quad * 8];
      acc[0][nt] = __builtin_amdgcn_mfma_f32_16x16x32_bf16(a0[kk], b, acc[0][nt], 0, 0, 0);
      acc[1][nt] = __builtin_amdgcn_mfma_f32_16x16x32_bf16(a1[kk], b, acc[1][nt], 0, 0, 0);
    }
  }
  #pragma unroll
  for (int mt = 0; mt < 2; ++mt)
    #pragma unroll
    for (int nt = 0; nt < 8; ++nt)
      #pragma unroll
      for (int r = 0; r < 4; ++r){
        int row = rowbase + mt * 16 + quad * 4 + r;
        if (row < N_NODES)
          Y[(size_t)row * 128 + nt * 16 + l15] = (unsigned short)f2bf(acc[mt][nt][r]);
      }
}

// ---------------- MFMA GEMM on bf16 input (layers 1,2) ----------------

__global__ __launch_bounds__(256) void gemm_mfma(const unsigned short* __restrict__ A,
                                                 const unsigned short* __restrict__ Wt,
                                                 unsigned short* __restrict__ Y){
  __shared__ unsigned short ldsb[128 * 136];
  int tid = threadIdx.x;
  #pragma unroll
  for (int it = 0; it < 8; ++it){
    int c  = tid + it * 256;
    int n  = c >> 4, kc = c & 15;
    *(short8*)&ldsb[n * 136 + kc * 8] = *(const short8*)(Wt + n * 128 + kc * 8);
  }
  int wave = tid >> 6, lane = tid & 63, quad = lane >> 4, l15 = lane & 15;
  int rowbase = blockIdx.x * 128 + wave * 32;
  int rm0 = rowbase + l15;      if (rm0 > N_NODES - 1) rm0 = N_NODES - 1;
  int rm1 = rowbase + 16 + l15; if (rm1 > N_NODES - 1) rm1 = N_NODES - 1;

  short8 a0[4], a1[4];
  #pragma unroll
  for (int kk = 0; kk < 4; ++kk){
    a0[kk] = *(const short8*)(A + (size_t)rm0 * 128 + kk * 32 + quad * 8);
    a1[kk] = *(const short8*)(A + (size_t)rm1 * 128 + kk * 32 + quad * 8);
  }
  f32x4 acc[2][8];
  #pragma unroll
  for (int mt = 0; mt < 2; ++mt)
    #pragma unroll
    for (int nt = 0; nt < 8; ++nt) acc[mt][nt] = (f32x4){0.f, 0.f, 0.f, 0.f};
  __syncthreads();
  #pragma unroll
  for (int kk = 0; kk < 4; ++kk){
    #pragma unroll
    for (int nt = 0; nt < 8; ++nt){
      short8 b = *(const short8*)&ldsb[(nt * 16 + l15) * 136 + kk * 32 + quad * 8];
      acc[0][nt] = __builtin_amdgcn_mfma_f32_16x16x32_bf16(a0[kk], b, acc[0][nt], 0, 0, 0);
      acc[1][nt] = __builtin_amdgcn_mfma_f32_16x16x32_bf16(a1[kk], b, acc[1][nt], 0, 0, 0);
    }
  }
  #pragma unroll
  for (int mt = 0; mt < 2; ++mt)
    #pragma unroll
    for (int nt = 0; nt < 8; ++nt)
      #pragma unroll
      for (int r = 0; r < 4; ++r){
        int row = rowbase + mt * 16 + quad * 4 + r;
        if (row < N_NODES)
          Y[(size_t)row * 128 + nt * 16 + l15] = (unsigned short)f2bf(acc[mt][nt][r]);
      }
}

// ---------------- Aggregate: 4 nodes/wave, packed ELL, PIPELINED gathers ----------------
// Wave = 4 groups of 16 lanes; group g -> node wave*4+g; lane hl holds feats [hl*8, hl*8+8).
// Chunk c+1's 4 gathers issue before chunk c's FMAs consume -> ~8 loads in flight/wave.

template<bool HAS_RES, bool DO_LN>
__global__ __launch_bounds__(256) void agg_kernel(const unsigned short* __restrict__ y,
                                                  const int* __restrict__ cnt,
                                                  const unsigned int* __restrict__ ell,
                                                  const float* __restrict__ bias,
                                                  const float* __restrict__ res,
                                                  float* __restrict__ outp,
                                                  const float* __restrict__ lng,
                                                  const float* __restrict__ lnb,
                                                  unsigned short* __restrict__ hn_out){
  int wv   = (blockIdx.x * 256 + threadIdx.x) >> 6;  // 12500 waves exactly (50000/4)
  int lane = threadIdx.x & 63;
  int hl   = lane & 15;
  int node = wv * 4 + (lane >> 4);
  int selbase = lane & 48;
  const uint4* y4 = (const uint4*)y;                 // row = 16 uint4

  int deg = cnt[node];
  float di = rsqrtf((float)(deg + 1));
  float ws = di * di;                                // self-loop weight

  const unsigned int* row = ell + (size_t)node * ELLW;
  unsigned int e0 = row[hl], e1 = row[hl + 16], e2 = row[hl + 32], e3 = row[hl + 48];

  int J = deg;
  J = max(J, __shfl_xor(J, 16, 64));
  J = max(J, __shfl_xor(J, 32, 64));

  uint4 us = y4[(size_t)node * 16 + hl];
  float acc0 = ws * bflo(us.x), acc1 = ws * bfhi(us.x);
  float acc2 = ws * bflo(us.y), acc3 = ws * bfhi(us.y);
  float acc4 = ws * bflo(us.z), acc5 = ws * bfhi(us.z);
  float acc6 = ws * bflo(us.w), acc7 = ws * bfhi(us.w);

  auto fma4 = [&](unsigned int p, uint4 gg){
    float w = bfhi(p);
    acc0 += w*bflo(gg.x); acc1 += w*bfhi(gg.x); acc2 += w*bflo(gg.y); acc3 += w*bfhi(gg.y);
    acc4 += w*bflo(gg.z); acc5 += w*bfhi(gg.z); acc6 += w*bflo(gg.w); acc7 += w*bfhi(gg.w);
  };

  auto block16 = [&](unsigned int ee, int base16){
    int rem = J - base16;
    if (rem <= 0) return;
    int nch = (min(rem, 16) + 3) >> 2;               // wave-uniform chunk count
    unsigned int p[4]; uint4 g[4];
    #pragma unroll
    for (int j = 0; j < 4; ++j) p[j] = (unsigned)__shfl((int)ee, selbase | j, 64);
    #pragma unroll
    for (int j = 0; j < 4; ++j) g[j] = y4[(size_t)(p[j] & 0xFFFFu) * 16 + hl];
    for (int c = 0; c + 1 < nch; ++c){
      unsigned int pn[4]; uint4 gn[4];
      int rb = (c + 1) * 4;
      #pragma unroll
      for (int j = 0; j < 4; ++j) pn[j] = (unsigned)__shfl((int)ee, selbase | (rb + j), 64);
      #pragma unroll
      for (int j = 0; j < 4; ++j) gn[j] = y4[(size_t)(pn[j] & 0xFFFFu) * 16 + hl];
      #pragma unroll
      for (int j = 0; j < 4; ++j) fma4(p[j], g[j]);
      #pragma unroll
      for (int j = 0; j < 4; ++j){ p[j] = pn[j]; g[j] = gn[j]; }
    }
    #pragma unroll
    for (int j = 0; j < 4; ++j) fma4(p[j], g[j]);
  };
  block16(e0, 0); block16(e1, 16); block16(e2, 32); block16(e3, 48);

  float4 ubA = ((const float4*)bias)[hl * 2];
  float4 ubB = ((const float4*)bias)[hl * 2 + 1];
  acc0 += ubA.x; acc1 += ubA.y; acc2 += ubA.z; acc3 += ubA.w;
  acc4 += ubB.x; acc5 += ubB.y; acc6 += ubB.z; acc7 += ubB.w;
  if (HAS_RES){
    float4 urA = ((const float4*)res)[(size_t)node * 32 + hl * 2];
    float4 urB = ((const float4*)res)[(size_t)node * 32 + hl * 2 + 1];
    acc0 += urA.x; acc1 += urA.y; acc2 += urA.z; acc3 += urA.w;
    acc4 += urB.x; acc5 += urB.y; acc6 += urB.z; acc7 += urB.w;
  }
  if (outp){
    float4 oA; oA.x = acc0; oA.y = acc1; oA.z = acc2; oA.w = acc3;
    float4 oB; oB.x = acc4; oB.y = acc5; oB.z = acc6; oB.w = acc7;
    ((float4*)outp)[(size_t)node * 32 + hl * 2]     = oA;
    ((float4*)outp)[(size_t)node * 32 + hl * 2 + 1] = oB;
  }

  if (DO_LN){
    float s  = acc0 + acc1 + acc2 + acc3 + acc4 + acc5 + acc6 + acc7;
    float ss = acc0*acc0 + acc1*acc1 + acc2*acc2 + acc3*acc3
             + acc4*acc4 + acc5*acc5 + acc6*acc6 + acc7*acc7;
    #pragma unroll
    for (int d = 8; d >= 1; d >>= 1){ s += __shfl_xor(s, d, 64); ss += __shfl_xor(ss, d, 64); }
    float mu  = s * (1.0f / 128.0f);
    float var = ss * (1.0f / 128.0f) - mu * mu;
    float rs  = rsqrtf(var + 1e-5f);
    float4 ugA = ((const float4*)lng)[hl * 2];
    float4 ugB = ((const float4*)lng)[hl * 2 + 1];
    float4 ubbA = ((const float4*)lnb)[hl * 2];
    float4 ubbB = ((const float4*)lnb)[hl * 2 + 1];
    float h0 = fmaxf((acc0 - mu) * rs * ugA.x + ubbA.x, 0.0f);
    float h1 = fmaxf((acc1 - mu) * rs * ugA.y + ubbA.y, 0.0f);
    float h2 = fmaxf((acc2 - mu) * rs * ugA.z + ubbA.z, 0.0f);
    float h3 = fmaxf((acc3 - mu) * rs * ugA.w + ubbA.w, 0.0f);
    float h4 = fmaxf((acc4 - mu) * rs * ugB.x + ubbB.x, 0.0f);
    float h5 = fmaxf((acc5 - mu) * rs * ugB.y + ubbB.y, 0.0f);
    float h6 = fmaxf((acc6 - mu) * rs * ugB.z + ubbB.z, 0.0f);
    float h7 = fmaxf((acc7 - mu) * rs * ugB.w + ubbB.w, 0.0f);
    uint4 ho;
    ho.x = pack2(h0, h1); ho.y = pack2(h2, h3);
    ho.z = pack2(h4, h5); ho.w = pack2(h6, h7);
    ((uint4*)hn_out)[(size_t)node * 16 + hl] = ho;
  }
}

// ---------------- launch ----------------

extern "C" void kernel_launch(void* const* d_in, const int* in_sizes, int n_in,
                              void* d_out, int out_size, void* d_ws, size_t ws_size,
                              hipStream_t stream){
  const float* x    = (const float*)d_in[0];
  const int*   edges= (const int*)d_in[1];
  const float* lng0 = (const float*)d_in[2];
  const float* lnb0 = (const float*)d_in[3];
  const float* W0   = (const float*)d_in[4];
  const float* b0   = (const float*)d_in[5];
  const float* lng1 = (const float*)d_in[6];
  const float* lnb1 = (const float*)d_in[7];
  const float* W1   = (const float*)d_in[8];
  const float* b1   = (const float*)d_in[9];
  const float* lng2 = (const float*)d_in[10];
  const float* lnb2 = (const float*)d_in[11];
  const float* W2   = (const float*)d_in[12];
  const float* b2   = (const float*)d_in[13];

  char* p = (char*)d_ws;
  auto carve = [&](size_t bytes) -> void* {
    void* r = (void*)p;
    p += (bytes + 255) & ~(size_t)255;
    return r;
  };
  int*          cnt  = (int*)         carve(N_NODES * 4);
  int*          epos = (int*)         carve((size_t)E_EDGES * 4);
  unsigned int* ell  = (unsigned int*)carve((size_t)N_NODES * ELLW * 4);   // 12.8 MB packed
  unsigned short* Wt = (unsigned short*)carve(3 * 128 * 128 * 2);
  unsigned short* hn = (unsigned short*)carve((size_t)N_NODES * 128 * 2);
  unsigned short* yb = (unsigned short*)carve((size_t)N_NODES * 128 * 2);
  float* out = (float*)d_out;   // doubles as x1 storage (layer-0 residual output)

  hipMemsetAsync(cnt, 0, N_NODES * 4, stream);   // 200 KB only

  count_kernel<<<(E_EDGES + 255) / 256, 256, 0, stream>>>(edges, cnt, epos);
  prep_kernel<<<3513, 256, 0, stream>>>(edges, epos, cnt, ell, W0, W1, W2, Wt);

  const int GEMM_GRID = (N_NODES + 127) / 128;      // 391
  const int AGG_GRID  = N_NODES / 4 / 4;            // 3125 blocks = 12500 waves, exact

  // layer 0: y = relu(LN0(x))@W0 (fused) ; x1 = agg(y)+b0+x -> d_out ; fused LN1 -> hn
  gemm_ln_mfma<<<GEMM_GRID, 256, 0, stream>>>(x, lng0, lnb0, Wt, yb);
  agg_kernel<true, true><<<AGG_GRID, 256, 0, stream>>>(yb, cnt, ell,
                                                       b0, x, out, lng1, lnb1, hn);
  // layer 1: y = hn@W1 ; h1 = agg(y)+b1 (not materialized) ; fused LN2(h1) -> hn
  gemm_mfma<<<GEMM_GRID, 256, 0, stream>>>(hn, Wt + 16384, yb);
  agg_kernel<false, true><<<AGG_GRID, 256, 0, stream>>>(yb, cnt, ell,
                                                        b1, nullptr, nullptr, lng2, lnb2, hn);
  // layer 2: y = hn@W2 ; out = agg(y)+b2+x1  (x1 read from d_out, overwritten in place)
  gemm_mfma<<<GEMM_GRID, 256, 0, stream>>>(hn, Wt + 32768, yb);
  agg_kernel<true, false><<<AGG_GRID, 256, 0, stream>>>(yb, cnt, ell,
                                                        b2, out, out, nullptr, nullptr, nullptr);
}

// Round 16
// 284.418 us; speedup vs baseline: 1.0311x; 1.0311x over previous
//
#include <hip/hip_runtime.h>

#define N_NODES 50000
#define DIM     128
#define E_EDGES 800000
#define ELLW    64        // ELL row stride; Poisson(16) in-degree, P(deg > 60) ~ 1e-18

typedef __attribute__((ext_vector_type(8))) short short8;
typedef __attribute__((ext_vector_type(4))) float f32x4;

__device__ __forceinline__ float bflo(unsigned int u){ return __uint_as_float(u << 16); }
__device__ __forceinline__ float bfhi(unsigned int u){ return __uint_as_float(u & 0xFFFF0000u); }
__device__ __forceinline__ unsigned int f2bf(float f){
  unsigned int u = __float_as_uint(f);
  return (u + 0x7FFFu + ((u >> 16) & 1u)) >> 16;
}
__device__ __forceinline__ unsigned int pack2(float a, float b){
  return f2bf(a) | (f2bf(b) << 16);
}

// ---------------- count: atomics + per-edge slot record ----------------

__global__ __launch_bounds__(256) void count_kernel(const int* __restrict__ edges,
                                                    int* __restrict__ cnt,
                                                    int* __restrict__ epos){
  int e = blockIdx.x * 256 + threadIdx.x;
  if (e < E_EDGES) epos[e] = atomicAdd(&cnt[edges[E_EDGES + e]], 1);
}

// ---------------- prep: fill ELL | pad ELL | cvt W -> bf16 Wt^T (block ranges) ------
// ELL entry = 4 B: lo16 = src node id (N<65536), hi16 = bf16 edge weight.
// blocks [0,3125): fill; [3125,3321): pad; [3321,3513): cvtw.

__global__ __launch_bounds__(256) void prep_kernel(const int* __restrict__ edges,
                                                   const int* __restrict__ epos,
                                                   const int* __restrict__ cnt,
                                                   unsigned int* __restrict__ ell,
                                                   const float* __restrict__ W0,
                                                   const float* __restrict__ W1,
                                                   const float* __restrict__ W2,
                                                   unsigned short* __restrict__ Wt){
  int u = blockIdx.x, tid = threadIdx.x;
  if (u < 3125){
    int e = u * 256 + tid;
    if (e < E_EDGES){
      int s = edges[e];
      int d = edges[E_EDGES + e];
      int pos = epos[e];
      if (pos < ELLW){
        float w = rsqrtf((float)(cnt[s] + 1)) * rsqrtf((float)(cnt[d] + 1));
        ell[(size_t)d * ELLW + pos] = (unsigned)s | (f2bf(w) << 16);
      }
    }
  } else if (u < 3125 + 196){
    int i = (u - 3125) * 256 + tid;
    if (i < N_NODES){
      int deg = cnt[i];
      int g4 = i & ~3;   // agg wave covers nodes [g4, g4+4) with shared J
      int J = max(max(cnt[g4], cnt[g4 + 1]), max(cnt[g4 + 2], cnt[g4 + 3]));
      int J4 = min(ELLW, (J + 3) & ~3);
      for (int pp = min(deg, J4); pp < J4; ++pp)
        ell[(size_t)i * ELLW + pp] = 0u;        // src=0, w=+0.0bf16
    }
  } else {
    int idx = (u - 3321) * 256 + tid;   // < 49152
    int w = idx >> 14, r = idx & 16383;
    const float* W = (w == 0) ? W0 : (w == 1) ? W1 : W2;
    Wt[w * 16384 + (r & 127) * 128 + (r >> 7)] = (unsigned short)f2bf(W[r]);
  }
}

// ---------------- GEMM with fused LN+ReLU, M=64 tile (4 waves x 16 rows) ----------------
// 782 blocks = 3.05 blocks/CU (vs 1.53 at M=128): finer scheduling quantization.

__global__ __launch_bounds__(256) void gemm_ln_mfma(const float* __restrict__ X,
                                                    const float* __restrict__ g,
                                                    const float* __restrict__ bt,
                                                    const unsigned short* __restrict__ Wt,
                                                    unsigned short* __restrict__ Y){
  __shared__ unsigned short ldsb[128 * 136];
  int tid = threadIdx.x;
  #pragma unroll
  for (int it = 0; it < 8; ++it){
    int c  = tid + it * 256;
    int n  = c >> 4, kc = c & 15;
    *(short8*)&ldsb[n * 136 + kc * 8] = *(const short8*)(Wt + n * 128 + kc * 8);
  }
  int wave = tid >> 6, lane = tid & 63, quad = lane >> 4, l15 = lane & 15;
  int rbase = blockIdx.x * 64 + wave * 16;
  int rm = rbase + l15; if (rm > N_NODES - 1) rm = N_NODES - 1;

  float v[4][8];
  float s = 0.f, ss = 0.f;
  #pragma unroll
  for (int kk = 0; kk < 4; ++kk){
    float4 xa = *(const float4*)(X + (size_t)rm * 128 + kk * 32 + quad * 8);
    float4 xb = *(const float4*)(X + (size_t)rm * 128 + kk * 32 + quad * 8 + 4);
    v[kk][0]=xa.x; v[kk][1]=xa.y; v[kk][2]=xa.z; v[kk][3]=xa.w;
    v[kk][4]=xb.x; v[kk][5]=xb.y; v[kk][6]=xb.z; v[kk][7]=xb.w;
    #pragma unroll
    for (int j = 0; j < 8; ++j){ s += v[kk][j]; ss += v[kk][j] * v[kk][j]; }
  }
  s += __shfl_xor(s, 16, 64); ss += __shfl_xor(ss, 16, 64);
  s += __shfl_xor(s, 32, 64); ss += __shfl_xor(ss, 32, 64);
  float mu = s * (1.0f/128.0f), var = ss * (1.0f/128.0f) - mu * mu;
  float rs = rsqrtf(var + 1e-5f);
  short8 a[4];
  #pragma unroll
  for (int kk = 0; kk < 4; ++kk){
    float4 ga = *(const float4*)(g  + kk * 32 + quad * 8);
    float4 gb = *(const float4*)(g  + kk * 32 + quad * 8 + 4);
    float4 ba = *(const float4*)(bt + kk * 32 + quad * 8);
    float4 bb = *(const float4*)(bt + kk * 32 + quad * 8 + 4);
    float gg[8]  = {ga.x,ga.y,ga.z,ga.w,gb.x,gb.y,gb.z,gb.w};
    float bbv[8] = {ba.x,ba.y,ba.z,ba.w,bb.x,bb.y,bb.z,bb.w};
    #pragma unroll
    for (int j = 0; j < 8; ++j){
      float h = fmaxf((v[kk][j] - mu) * rs * gg[j] + bbv[j], 0.0f);
      a[kk][j] = (short)f2bf(h);
    }
  }
  f32x4 acc[8];
  #pragma unroll
  for (int nt = 0; nt < 8; ++nt) acc[nt] = (f32x4){0.f, 0.f, 0.f, 0.f};
  __syncthreads();
  #pragma unroll
  for (int kk = 0; kk < 4; ++kk)
    #pragma unroll
    for (int nt = 0; nt < 8; ++nt){
      short8 b = *(const short8*)&ldsb[(nt * 16 + l15) * 136 + kk * 32 + quad * 8];
      acc[nt] = __builtin_amdgcn_mfma_f32_16x16x32_bf16(a[kk], b, acc[nt], 0, 0, 0);
    }
  #pragma unroll
  for (int nt = 0; nt < 8; ++nt)
    #pragma unroll
    for (int r = 0; r < 4; ++r){
      int row = rbase + quad * 4 + r;
      if (row < N_NODES)
        Y[(size_t)row * 128 + nt * 16 + l15] = (unsigned short)f2bf(acc[nt][r]);
    }
}

// ---------------- MFMA GEMM on bf16 input, M=64 tile (layers 1,2) ----------------

__global__ __launch_bounds__(256) void gemm_mfma(const unsigned short* __restrict__ A,
                                                 const unsigned short* __restrict__ Wt,
                                                 unsigned short* __restrict__ Y){
  __shared__ unsigned short ldsb[128 * 136];
  int tid = threadIdx.x;
  #pragma unroll
  for (int it = 0; it < 8; ++it){
    int c  = tid + it * 256;
    int n  = c >> 4, kc = c & 15;
    *(short8*)&ldsb[n * 136 + kc * 8] = *(const short8*)(Wt + n * 128 + kc * 8);
  }
  int wave = tid >> 6, lane = tid & 63, quad = lane >> 4, l15 = lane & 15;
  int rbase = blockIdx.x * 64 + wave * 16;
  int rm = rbase + l15; if (rm > N_NODES - 1) rm = N_NODES - 1;

  short8 a[4];
  #pragma unroll
  for (int kk = 0; kk < 4; ++kk)
    a[kk] = *(const short8*)(A + (size_t)rm * 128 + kk * 32 + quad * 8);
  f32x4 acc[8];
  #pragma unroll
  for (int nt = 0; nt < 8; ++nt) acc[nt] = (f32x4){0.f, 0.f, 0.f, 0.f};
  __syncthreads();
  #pragma unroll
  for (int kk = 0; kk < 4; ++kk)
    #pragma unroll
    for (int nt = 0; nt < 8; ++nt){
      short8 b = *(const short8*)&ldsb[(nt * 16 + l15) * 136 + kk * 32 + quad * 8];
      acc[nt] = __builtin_amdgcn_mfma_f32_16x16x32_bf16(a[kk], b, acc[nt], 0, 0, 0);
    }
  #pragma unroll
  for (int nt = 0; nt < 8; ++nt)
    #pragma unroll
    for (int r = 0; r < 4; ++r){
      int row = rbase + quad * 4 + r;
      if (row < N_NODES)
        Y[(size_t)row * 128 + nt * 16 + l15] = (unsigned short)f2bf(acc[nt][r]);
    }
}

// ---------------- Aggregate: 4 nodes/wave, uint4 gathers, packed 4-B ELL ----------------
// (round-14 proven form; pipelined variant was neutral->reverted)

template<bool HAS_RES, bool DO_LN>
__global__ __launch_bounds__(256) void agg_kernel(const unsigned short* __restrict__ y,
                                                  const int* __restrict__ cnt,
                                                  const unsigned int* __restrict__ ell,
                                                  const float* __restrict__ bias,
                                                  const float* __restrict__ res,
                                                  float* __restrict__ outp,
                                                  const float* __restrict__ lng,
                                                  const float* __restrict__ lnb,
                                                  unsigned short* __restrict__ hn_out){
  int wv   = (blockIdx.x * 256 + threadIdx.x) >> 6;  // 12500 waves exactly (50000/4)
  int lane = threadIdx.x & 63;
  int hl   = lane & 15;
  int node = wv * 4 + (lane >> 4);
  int selbase = lane & 48;
  const uint4* y4 = (const uint4*)y;                 // row = 16 uint4

  int deg = cnt[node];
  float di = rsqrtf((float)(deg + 1));
  float ws = di * di;                                // self-loop weight

  const unsigned int* row = ell + (size_t)node * ELLW;
  unsigned int e0 = row[hl], e1 = row[hl + 16], e2 = row[hl + 32], e3 = row[hl + 48];

  int J = deg;
  J = max(J, __shfl_xor(J, 16, 64));
  J = max(J, __shfl_xor(J, 32, 64));

  uint4 us = y4[(size_t)node * 16 + hl];
  float acc0 = ws * bflo(us.x), acc1 = ws * bfhi(us.x);
  float acc2 = ws * bflo(us.y), acc3 = ws * bfhi(us.y);
  float acc4 = ws * bflo(us.z), acc5 = ws * bfhi(us.z);
  float acc6 = ws * bflo(us.w), acc7 = ws * bfhi(us.w);

  auto block16 = [&](unsigned int ee, int base16){
    int rem = J - base16;
    if (rem <= 0) return;
    int nch = (min(rem, 16) + 3) >> 2;               // wave-uniform chunk count
    for (int c = 0; c < nch; ++c){
      int rb = c * 4;
      unsigned int pA = (unsigned)__shfl((int)ee, selbase | (rb + 0), 64);
      unsigned int pB = (unsigned)__shfl((int)ee, selbase | (rb + 1), 64);
      unsigned int pC = (unsigned)__shfl((int)ee, selbase | (rb + 2), 64);
      unsigned int pD = (unsigned)__shfl((int)ee, selbase | (rb + 3), 64);
      uint4 gA = y4[(size_t)(pA & 0xFFFFu) * 16 + hl];
      uint4 gB = y4[(size_t)(pB & 0xFFFFu) * 16 + hl];
      uint4 gC = y4[(size_t)(pC & 0xFFFFu) * 16 + hl];
      uint4 gD = y4[(size_t)(pD & 0xFFFFu) * 16 + hl];
      float wA = bfhi(pA), wB = bfhi(pB), wC = bfhi(pC), wD = bfhi(pD);
      acc0 += wA*bflo(gA.x); acc1 += wA*bfhi(gA.x); acc2 += wA*bflo(gA.y); acc3 += wA*bfhi(gA.y);
      acc4 += wA*bflo(gA.z); acc5 += wA*bfhi(gA.z); acc6 += wA*bflo(gA.w); acc7 += wA*bfhi(gA.w);
      acc0 += wB*bflo(gB.x); acc1 += wB*bfhi(gB.x); acc2 += wB*bflo(gB.y); acc3 += wB*bfhi(gB.y);
      acc4 += wB*bflo(gB.z); acc5 += wB*bfhi(gB.z); acc6 += wB*bflo(gB.w); acc7 += wB*bfhi(gB.w);
      acc0 += wC*bflo(gC.x); acc1 += wC*bfhi(gC.x); acc2 += wC*bflo(gC.y); acc3 += wC*bfhi(gC.y);
      acc4 += wC*bflo(gC.z); acc5 += wC*bfhi(gC.z); acc6 += wC*bflo(gC.w); acc7 += wC*bfhi(gC.w);
      acc0 += wD*bflo(gD.x); acc1 += wD*bfhi(gD.x); acc2 += wD*bflo(gD.y); acc3 += wD*bfhi(gD.y);
      acc4 += wD*bflo(gD.z); acc5 += wD*bfhi(gD.z); acc6 += wD*bflo(gD.w); acc7 += wD*bfhi(gD.w);
    }
  };
  block16(e0, 0); block16(e1, 16); block16(e2, 32); block16(e3, 48);

  float4 ubA = ((const float4*)bias)[hl * 2];
  float4 ubB = ((const float4*)bias)[hl * 2 + 1];
  acc0 += ubA.x; acc1 += ubA.y; acc2 += ubA.z; acc3 += ubA.w;
  acc4 += ubB.x; acc5 += ubB.y; acc6 += ubB.z; acc7 += ubB.w;
  if (HAS_RES){
    float4 urA = ((const float4*)res)[(size_t)node * 32 + hl * 2];
    float4 urB = ((const float4*)res)[(size_t)node * 32 + hl * 2 + 1];
    acc0 += urA.x; acc1 += urA.y; acc2 += urA.z; acc3 += urA.w;
    acc4 += urB.x; acc5 += urB.y; acc6 += urB.z; acc7 += urB.w;
  }
  if (outp){
    float4 oA; oA.x = acc0; oA.y = acc1; oA.z = acc2; oA.w = acc3;
    float4 oB; oB.x = acc4; oB.y = acc5; oB.z = acc6; oB.w = acc7;
    ((float4*)outp)[(size_t)node * 32 + hl * 2]     = oA;
    ((float4*)outp)[(size_t)node * 32 + hl * 2 + 1] = oB;
  }

  if (DO_LN){
    float s  = acc0 + acc1 + acc2 + acc3 + acc4 + acc5 + acc6 + acc7;
    float ss = acc0*acc0 + acc1*acc1 + acc2*acc2 + acc3*acc3
             + acc4*acc4 + acc5*acc5 + acc6*acc6 + acc7*acc7;
    #pragma unroll
    for (int d = 8; d >= 1; d >>= 1){ s += __shfl_xor(s, d, 64); ss += __shfl_xor(ss, d, 64); }
    float mu  = s * (1.0f / 128.0f);
    float var = ss * (1.0f / 128.0f) - mu * mu;
    float rs  = rsqrtf(var + 1e-5f);
    float4 ugA = ((const float4*)lng)[hl * 2];
    float4 ugB = ((const float4*)lng)[hl * 2 + 1];
    float4 ubbA = ((const float4*)lnb)[hl * 2];
    float4 ubbB = ((const float4*)lnb)[hl * 2 + 1];
    float h0 = fmaxf((acc0 - mu) * rs * ugA.x + ubbA.x, 0.0f);
    float h1 = fmaxf((acc1 - mu) * rs * ugA.y + ubbA.y, 0.0f);
    float h2 = fmaxf((acc2 - mu) * rs * ugA.z + ubbA.z, 0.0f);
    float h3 = fmaxf((acc3 - mu) * rs * ugA.w + ubbA.w, 0.0f);
    float h4 = fmaxf((acc4 - mu) * rs * ugB.x + ubbB.x, 0.0f);
    float h5 = fmaxf((acc5 - mu) * rs * ugB.y + ubbB.y, 0.0f);
    float h6 = fmaxf((acc6 - mu) * rs * ugB.z + ubbB.z, 0.0f);
    float h7 = fmaxf((acc7 - mu) * rs * ugB.w + ubbB.w, 0.0f);
    uint4 ho;
    ho.x = pack2(h0, h1); ho.y = pack2(h2, h3);
    ho.z = pack2(h4, h5); ho.w = pack2(h6, h7);
    ((uint4*)hn_out)[(size_t)node * 16 + hl] = ho;
  }
}

// ---------------- launch ----------------

extern "C" void kernel_launch(void* const* d_in, const int* in_sizes, int n_in,
                              void* d_out, int out_size, void* d_ws, size_t ws_size,
                              hipStream_t stream){
  const float* x    = (const float*)d_in[0];
  const int*   edges= (const int*)d_in[1];
  const float* lng0 = (const float*)d_in[2];
  const float* lnb0 = (const float*)d_in[3];
  const float* W0   = (const float*)d_in[4];
  const float* b0   = (const float*)d_in[5];
  const float* lng1 = (const float*)d_in[6];
  const float* lnb1 = (const float*)d_in[7];
  const float* W1   = (const float*)d_in[8];
  const float* b1   = (const float*)d_in[9];
  const float* lng2 = (const float*)d_in[10];
  const float* lnb2 = (const float*)d_in[11];
  const float* W2   = (const float*)d_in[12];
  const float* b2   = (const float*)d_in[13];

  char* p = (char*)d_ws;
  auto carve = [&](size_t bytes) -> void* {
    void* r = (void*)p;
    p += (bytes + 255) & ~(size_t)255;
    return r;
  };
  int*          cnt  = (int*)         carve(N_NODES * 4);
  int*          epos = (int*)         carve((size_t)E_EDGES * 4);
  unsigned int* ell  = (unsigned int*)carve((size_t)N_NODES * ELLW * 4);   // 12.8 MB packed
  unsigned short* Wt = (unsigned short*)carve(3 * 128 * 128 * 2);
  unsigned short* hn = (unsigned short*)carve((size_t)N_NODES * 128 * 2);
  unsigned short* yb = (unsigned short*)carve((size_t)N_NODES * 128 * 2);
  float* out = (float*)d_out;   // doubles as x1 storage (layer-0 residual output)

  hipMemsetAsync(cnt, 0, N_NODES * 4, stream);   // 200 KB only

  count_kernel<<<(E_EDGES + 255) / 256, 256, 0, stream>>>(edges, cnt, epos);
  prep_kernel<<<3513, 256, 0, stream>>>(edges, epos, cnt, ell, W0, W1, W2, Wt);

  const int GEMM_GRID = (N_NODES + 63) / 64;        // 782 blocks = 3.05/CU
  const int AGG_GRID  = N_NODES / 4 / 4;            // 3125 blocks = 12500 waves, exact

  // layer 0: y = relu(LN0(x))@W0 (fused) ; x1 = agg(y)+b0+x -> d_out ; fused LN1 -> hn
  gemm_ln_mfma<<<GEMM_GRID, 256, 0, stream>>>(x, lng0, lnb0, Wt, yb);
  agg_kernel<true, true><<<AGG_GRID, 256, 0, stream>>>(yb, cnt, ell,
                                                       b0, x, out, lng1, lnb1, hn);
  // layer 1: y = hn@W1 ; h1 = agg(y)+b1 (not materialized) ; fused LN2(h1) -> hn
  gemm_mfma<<<GEMM_GRID, 256, 0, stream>>>(hn, Wt + 16384, yb);
  agg_kernel<false, true><<<AGG_GRID, 256, 0, stream>>>(yb, cnt, ell,
                                                        b1, nullptr, nullptr, lng2, lnb2, hn);
  // layer 2: y = hn@W2 ; out = agg(y)+b2+x1  (x1 read from d_out, overwritten in place)
  gemm_mfma<<<GEMM_GRID, 256, 0, stream>>>(hn, Wt + 32768, yb);
  agg_kernel<true, false><<<AGG_GRID, 256, 0, stream>>>(yb, cnt, ell,
                                                        b2, out, out, nullptr, nullptr, nullptr);
}